// Round 1
// baseline (901.634 us; speedup 1.0000x reference)
//
#include <hip/hip_runtime.h>
#include <stdint.h>

// ---------------------------------------------------------------------------
// Predictor: MLP (256->512->256->128, fp32) -> LSTM(128 in, 256 hidden, T=50)
// Strategy:
//   - MLP + x_part in fp32 (tiled VALU GEMM, accuracy-critical systematic path)
//   - LSTM recurrence: persistent kernel, 32 batch rows per WG, 50 steps in-WG.
//     h @ W_hh^T via bf16 MFMA 16x16x32 (HW-verified A/C layouts), c-state in
//     VGPRs, h double-buffered in LDS in A-fragment layout, W_hh pre-packed in
//     B-fragment layout (coalesced 16B/lane loads, L2-resident).
// ---------------------------------------------------------------------------

typedef short short8 __attribute__((ext_vector_type(8)));
typedef float floatx4 __attribute__((ext_vector_type(4)));

#define BATCH 4096
#define HID 256
#define TSTEPS 50

static __device__ __forceinline__ unsigned short f2bf(float x) {
  union { float f; unsigned int u; } v; v.f = x;
  unsigned int r = (v.u + 0x7fffu + ((v.u >> 16) & 1u)) >> 16;  // RNE
  return (unsigned short)r;
}

static __device__ __forceinline__ float sigmf(float x) {
  return __builtin_amdgcn_rcpf(1.0f + __expf(-x));
}
static __device__ __forceinline__ float tanhf_(float x) {
  // tanh(x) = 1 - 2/(e^{2x}+1); saturates correctly at +-inf
  return 1.0f - 2.0f * __builtin_amdgcn_rcpf(__expf(2.0f * x) + 1.0f);
}

// ---------------------------------------------------------------------------
// fp32 GEMM: C[m][n] = act(sum_k A[m][k]*B[n][k] + bias[n] (+ bias2[n]))
// A:[M,K] row-major, B:[N,K] row-major (torch Linear weight), 64x64 tile,
// 256 threads, 4x4 microtile, BK=16.
// ---------------------------------------------------------------------------
template<int RELU, int HAS_B2>
__global__ __launch_bounds__(256) void gemm_bt(
    const float* __restrict__ A, const float* __restrict__ B,
    const float* __restrict__ bias, const float* __restrict__ bias2,
    float* __restrict__ C, int M, int N, int K) {
  __shared__ float As[16][68];  // [k][m], pad to 68 for bank spread + 16B align
  __shared__ float Bs[16][68];  // [k][n]
  const int tid = threadIdx.x;
  const int bm = blockIdx.y * 64, bn = blockIdx.x * 64;
  const int lr = tid >> 2;           // 0..63 row loader
  const int lk = (tid & 3) * 4;      // k offset {0,4,8,12}
  const int tm = tid >> 4;           // 0..15
  const int tn = tid & 15;           // 0..15

  float acc[4][4] = {};
  for (int k0 = 0; k0 < K; k0 += 16) {
    float4 av = *(const float4*)(A + (size_t)(bm + lr) * K + k0 + lk);
    float4 bv = *(const float4*)(B + (size_t)(bn + lr) * K + k0 + lk);
    As[lk + 0][lr] = av.x; As[lk + 1][lr] = av.y;
    As[lk + 2][lr] = av.z; As[lk + 3][lr] = av.w;
    Bs[lk + 0][lr] = bv.x; Bs[lk + 1][lr] = bv.y;
    Bs[lk + 2][lr] = bv.z; Bs[lk + 3][lr] = bv.w;
    __syncthreads();
#pragma unroll
    for (int kk = 0; kk < 16; ++kk) {
      float4 a4 = *(const float4*)&As[kk][tm * 4];
      float4 b4 = *(const float4*)&Bs[kk][tn * 4];
      float ar[4] = {a4.x, a4.y, a4.z, a4.w};
      float br[4] = {b4.x, b4.y, b4.z, b4.w};
#pragma unroll
      for (int i = 0; i < 4; ++i)
#pragma unroll
        for (int j = 0; j < 4; ++j)
          acc[i][j] = fmaf(ar[i], br[j], acc[i][j]);
    }
    __syncthreads();
  }
  float bj[4];
#pragma unroll
  for (int j = 0; j < 4; ++j) {
    bj[j] = bias[bn + tn * 4 + j];
    if (HAS_B2) bj[j] += bias2[bn + tn * 4 + j];
  }
#pragma unroll
  for (int i = 0; i < 4; ++i) {
    float4 o;
    o.x = acc[i][0] + bj[0]; o.y = acc[i][1] + bj[1];
    o.z = acc[i][2] + bj[2]; o.w = acc[i][3] + bj[3];
    if (RELU) {
      o.x = fmaxf(o.x, 0.f); o.y = fmaxf(o.y, 0.f);
      o.z = fmaxf(o.z, 0.f); o.w = fmaxf(o.w, 0.f);
    }
    *(float4*)(C + (size_t)(bm + tm * 4 + i) * N + bn + tn * 4) = o;
  }
}

// ---------------------------------------------------------------------------
// Pack W_hh [1024,256] fp32 -> bf16 B-fragment layout:
//   whhf[nt][kt][lane][j] = bf16( W_hh[nt*16 + (lane&15)][kt*32 + (lane>>4)*8 + j] )
// so a wave's 16B/lane load is exactly the MFMA B operand for tile (nt,kt).
// ---------------------------------------------------------------------------
__global__ __launch_bounds__(256) void pack_whh(const float* __restrict__ W,
                                                unsigned short* __restrict__ o) {
  int idx = blockIdx.x * 256 + threadIdx.x;  // 0..32767 = (nt*8+kt)*64+lane
  int lane = idx & 63;
  int kt = (idx >> 6) & 7;
  int nt = idx >> 9;
  int n = nt * 16 + (lane & 15);
  int k0 = kt * 32 + (lane >> 4) * 8;
  const float* src = W + (size_t)n * 256 + k0;
  unsigned short* dst = o + (size_t)idx * 8;
#pragma unroll
  for (int j = 0; j < 8; ++j) dst[j] = f2bf(src[j]);
}

// ---------------------------------------------------------------------------
// Persistent LSTM: 128 blocks x 512 threads (8 waves). Block owns 32 batch
// rows for all 50 timesteps. Wave w owns u-tiles {2w,2w+1} x all 4 gates
// (8 n-tiles) x 2 m-tiles -> 16 accumulator tiles. c-state lives in VGPRs in
// MFMA C-layout (row = quad*4+r, col = lane&15). h is written back to LDS in
// A-fragment layout (double-buffered; 1 barrier/step).
// ---------------------------------------------------------------------------
__global__ __launch_bounds__(512, 2) void lstm_kernel(
    const float* __restrict__ xp,            // [4096,1024] fp32, gates i|f|g|o
    const unsigned short* __restrict__ whhf, // packed bf16 fragments
    float* __restrict__ out) {               // [4096,50,256] fp32
  __shared__ unsigned short h_frag[2][2][8][64][8];  // [buf][mt][kt][lane][j]

  const int tid = threadIdx.x;
  const int wave = tid >> 6;
  const int lane = tid & 63;
  const int quad = lane >> 4;
  const int l16 = lane & 15;
  const int block_m = blockIdx.x * 32;
  const int ut0 = wave * 2;  // first u-tile of this wave

  // h0 = 0
  for (int i = tid; i < 2 * 2 * 8 * 64 * 8; i += 512)
    ((unsigned short*)h_frag)[i] = 0;

  // x_part cached in registers in C-fragment layout (re-seeds acc every step)
  floatx4 xpreg[2][2][4];  // [mt][utl][gate]
#pragma unroll
  for (int mt = 0; mt < 2; ++mt)
#pragma unroll
    for (int utl = 0; utl < 2; ++utl)
#pragma unroll
      for (int g = 0; g < 4; ++g) {
        int col = g * 256 + (ut0 + utl) * 16 + l16;
        floatx4 v;
#pragma unroll
        for (int r = 0; r < 4; ++r)
          v[r] = xp[(size_t)(block_m + mt * 16 + quad * 4 + r) * 1024 + col];
        xpreg[mt][utl][g] = v;
      }

  float c[2][2][4] = {};  // [mt][utl][r] cell state, in-register for all 50 steps
  __syncthreads();

  const size_t orow = (size_t)TSTEPS * HID;
  int cur = 0;

#pragma unroll 1
  for (int t = 0; t < TSTEPS; ++t) {
    // Opaque redefinition: stop LICM from hoisting t-invariant W_hh fragment
    // loads out of the T-loop (would need 256 VGPRs -> scratch spill).
    const unsigned short* wb = whhf;
    asm volatile("" : "+s"(wb));

    floatx4 acc[2][2][4];
#pragma unroll
    for (int mt = 0; mt < 2; ++mt)
#pragma unroll
      for (int utl = 0; utl < 2; ++utl)
#pragma unroll
        for (int g = 0; g < 4; ++g) acc[mt][utl][g] = xpreg[mt][utl][g];

    // gates += h @ W_hh^T  (K = 256 = 8 k-tiles of 32)
#pragma unroll
    for (int kt = 0; kt < 8; ++kt) {
      short8 a0 = *(const short8*)&h_frag[cur][0][kt][lane][0];
      short8 a1 = *(const short8*)&h_frag[cur][1][kt][lane][0];
#pragma unroll
      for (int utl = 0; utl < 2; ++utl)
#pragma unroll
        for (int g = 0; g < 4; ++g) {
          int nt = g * 16 + ut0 + utl;
          short8 b = *(const short8*)(wb + ((size_t)(nt * 8 + kt) * 64 + lane) * 8);
          acc[0][utl][g] =
              __builtin_amdgcn_mfma_f32_16x16x32_bf16(a0, b, acc[0][utl][g], 0, 0, 0);
          acc[1][utl][g] =
              __builtin_amdgcn_mfma_f32_16x16x32_bf16(a1, b, acc[1][utl][g], 0, 0, 0);
        }
    }

    const int nxt = cur ^ 1;
    // activations + state update + h write-back (C-layout -> A-layout via LDS)
#pragma unroll
    for (int mt = 0; mt < 2; ++mt)
#pragma unroll
      for (int utl = 0; utl < 2; ++utl) {
        floatx4 gi = acc[mt][utl][0];
        floatx4 gf = acc[mt][utl][1];
        floatx4 gg = acc[mt][utl][2];
        floatx4 go = acc[mt][utl][3];
        const int u = (ut0 + utl) * 16 + l16;
        const int kt2 = u >> 5;
        const int lhi = ((u >> 3) & 3) << 4;
        const int j2 = u & 7;
#pragma unroll
        for (int r = 0; r < 4; ++r) {
          float iv = sigmf(gi[r]);
          float fv = sigmf(gf[r]);
          float gv = tanhf_(gg[r]);
          float ov = sigmf(go[r]);
          float cv = fmaf(fv, c[mt][utl][r], iv * gv);
          c[mt][utl][r] = cv;
          float hv = ov * tanhf_(cv);
          int mloc = mt * 16 + quad * 4 + r;
          __builtin_nontemporal_store(
              hv, out + (size_t)(block_m + mloc) * orow + (size_t)t * HID + u);
          h_frag[nxt][mt][kt2][(mloc & 15) | lhi][j2] = f2bf(hv);
        }
      }
    cur = nxt;
    __syncthreads();  // writes to nxt visible; all reads of cur were pre-barrier
  }
}

// ---------------------------------------------------------------------------
extern "C" void kernel_launch(void* const* d_in, const int* in_sizes, int n_in,
                              void* d_out, int out_size, void* d_ws, size_t ws_size,
                              hipStream_t stream) {
  const float* zs  = (const float*)d_in[0];
  const float* W1  = (const float*)d_in[1];
  const float* b1  = (const float*)d_in[2];
  const float* W2  = (const float*)d_in[3];
  const float* b2  = (const float*)d_in[4];
  const float* W3  = (const float*)d_in[5];
  const float* b3  = (const float*)d_in[6];
  const float* Wih = (const float*)d_in[7];
  const float* Whh = (const float*)d_in[8];
  const float* bih = (const float*)d_in[9];
  const float* bhh = (const float*)d_in[10];
  float* out = (float*)d_out;

  char* ws = (char*)d_ws;
  float* h1 = (float*)(ws);                                  // 4096x512 fp32 (8 MB)
  float* h2 = (float*)(ws + (size_t)8 * 1024 * 1024);        // 4096x256 fp32 (4 MB)
  float* zb = (float*)(ws + (size_t)12 * 1024 * 1024);       // 4096x128 fp32 (2 MB)
  float* xp = (float*)(ws + (size_t)14 * 1024 * 1024);       // 4096x1024 fp32 (16 MB)
  unsigned short* whhf =
      (unsigned short*)(ws + (size_t)30 * 1024 * 1024);      // 512 KB bf16 frags

  // MLP (fp32): h1 = relu(zs@W1^T+b1); h2 = relu(h1@W2^T+b2); z = h2@W3^T+b3
  gemm_bt<1, 0><<<dim3(512 / 64, BATCH / 64), 256, 0, stream>>>(
      zs, W1, b1, nullptr, h1, BATCH, 512, 256);
  gemm_bt<1, 0><<<dim3(256 / 64, BATCH / 64), 256, 0, stream>>>(
      h1, W2, b2, nullptr, h2, BATCH, 256, 512);
  gemm_bt<0, 0><<<dim3(128 / 64, BATCH / 64), 256, 0, stream>>>(
      h2, W3, b3, nullptr, zb, BATCH, 128, 256);
  // x_part = z@W_ih^T + b_ih + b_hh
  gemm_bt<0, 1><<<dim3(1024 / 64, BATCH / 64), 256, 0, stream>>>(
      zb, Wih, bih, bhh, xp, BATCH, 1024, 128);

  pack_whh<<<128, 256, 0, stream>>>(Whh, whhf);

  lstm_kernel<<<BATCH / 32, 512, 0, stream>>>(xp, whhf, out);
}

// Round 2
// 851.112 us; speedup vs baseline: 1.0594x; 1.0594x over previous
//
#include <hip/hip_runtime.h>
#include <stdint.h>

// ---------------------------------------------------------------------------
// Predictor: MLP (256->512->256->128) -> LSTM(128 in, 256 hidden, T=50)
//   - MLP via split-bf16 (hi+lo) MFMA gemms: fp32-equivalent accuracy,
//     3 MFMA per tile (Ah*Bh + Ah*Bl + Al*Bh).
//   - LSTM: 128 blocks x 512 thr, M=32 rows/block, 50 steps in-kernel.
//     h @ W_hh^T via bf16 MFMA; B-fragments streamed from L2 with explicit
//     1-kt prefetch pipeline; raw lgkm-only barrier (no vmcnt drain) so
//     loads/stores pipeline across steps; c-state in VGPRs; h double-buffered
//     in LDS in A-fragment layout.
// ---------------------------------------------------------------------------

typedef short short8 __attribute__((ext_vector_type(8)));
typedef float floatx4 __attribute__((ext_vector_type(4)));
typedef unsigned short ushort4v __attribute__((ext_vector_type(4)));

#define BATCH 4096
#define HID 256
#define TSTEPS 50

static __device__ __forceinline__ unsigned short f2bf(float x) {
  union { float f; unsigned int u; } v; v.f = x;
  unsigned int r = (v.u + 0x7fffu + ((v.u >> 16) & 1u)) >> 16;  // RNE
  return (unsigned short)r;
}
static __device__ __forceinline__ float bf2f(unsigned short h) {
  union { unsigned int u; float f; } v; v.u = ((unsigned int)h) << 16;
  return v.f;
}
static __device__ __forceinline__ float sigmf(float x) {
  return __builtin_amdgcn_rcpf(1.0f + __expf(-x));
}
static __device__ __forceinline__ float tanhf_(float x) {
  return 1.0f - 2.0f * __builtin_amdgcn_rcpf(__expf(2.0f * x) + 1.0f);
}

// ---------------------------------------------------------------------------
// fp32 -> (hi, lo) bf16 split. n4 = count/4.
// ---------------------------------------------------------------------------
__global__ __launch_bounds__(256) void split_bf(const float* __restrict__ in,
                                                unsigned short* __restrict__ hi,
                                                unsigned short* __restrict__ lo,
                                                int n4) {
  int i = blockIdx.x * 256 + threadIdx.x;
  if (i >= n4) return;
  float4 v = ((const float4*)in)[i];
  float cc[4] = {v.x, v.y, v.z, v.w};
  ushort4v h, l;
#pragma unroll
  for (int j = 0; j < 4; ++j) {
    unsigned short hb = f2bf(cc[j]);
    h[j] = hb;
    l[j] = f2bf(cc[j] - bf2f(hb));
  }
  ((ushort4v*)hi)[i] = h;
  ((ushort4v*)lo)[i] = l;
}

// ---------------------------------------------------------------------------
// Split-bf16 MFMA GEMM: C = act(A @ B^T + bias (+bias2)), A:[M,K], B:[N,K]
// (both as hi/lo bf16 pairs, row-major). 64x64 tile, 256 thr (4 waves),
// BK=32, XOR-swizzled LDS (2-way conflict-free b128 reads).
// OUT_SPLIT: emit hi/lo bf16 pair; else fp32.
// ---------------------------------------------------------------------------
template <int RELU, int OUT_SPLIT, int HAS_B2>
__global__ __launch_bounds__(256) void gemm_df(
    const unsigned short* __restrict__ Ah, const unsigned short* __restrict__ Al,
    const unsigned short* __restrict__ Bh, const unsigned short* __restrict__ Bl,
    const float* __restrict__ bias, const float* __restrict__ bias2,
    float* __restrict__ Cf, unsigned short* __restrict__ Ch,
    unsigned short* __restrict__ Cl, int M, int N, int K) {
  __shared__ unsigned short Ash[64 * 32], Asl[64 * 32];
  __shared__ unsigned short Bsh[64 * 32], Bsl[64 * 32];
  const int tid = threadIdx.x;
  const int wave = tid >> 6, lane = tid & 63;
  const int quad = lane >> 4, l16 = lane & 15;
  const int bm = blockIdx.y * 64, bn = blockIdx.x * 64;
  const int lr = tid >> 2, lc = tid & 3;
  const int wofs = lr * 32 + ((lc ^ (lr & 3)) * 8);  // swizzled 16B chunk

  floatx4 acc[4] = {};
  for (int k0 = 0; k0 < K; k0 += 32) {
    short8 avh = *(const short8*)(Ah + (size_t)(bm + lr) * K + k0 + lc * 8);
    short8 avl = *(const short8*)(Al + (size_t)(bm + lr) * K + k0 + lc * 8);
    short8 bvh = *(const short8*)(Bh + (size_t)(bn + lr) * K + k0 + lc * 8);
    short8 bvl = *(const short8*)(Bl + (size_t)(bn + lr) * K + k0 + lc * 8);
    __syncthreads();  // prior iteration's LDS reads complete
    *(short8*)&Ash[wofs] = avh;
    *(short8*)&Asl[wofs] = avl;
    *(short8*)&Bsh[wofs] = bvh;
    *(short8*)&Bsl[wofs] = bvl;
    __syncthreads();
    const int bro = (wave * 16 + l16) * 32 + ((quad ^ (l16 & 3)) * 8);
    short8 bh = *(const short8*)&Bsh[bro];
    short8 bl = *(const short8*)&Bsl[bro];
#pragma unroll
    for (int i = 0; i < 4; ++i) {
      const int aro = (i * 16 + l16) * 32 + ((quad ^ (l16 & 3)) * 8);
      short8 ah = *(const short8*)&Ash[aro];
      short8 al = *(const short8*)&Asl[aro];
      acc[i] = __builtin_amdgcn_mfma_f32_16x16x32_bf16(al, bh, acc[i], 0, 0, 0);
      acc[i] = __builtin_amdgcn_mfma_f32_16x16x32_bf16(ah, bl, acc[i], 0, 0, 0);
      acc[i] = __builtin_amdgcn_mfma_f32_16x16x32_bf16(ah, bh, acc[i], 0, 0, 0);
    }
  }
  const int col = bn + wave * 16 + l16;
  float bj = bias[col];
  if (HAS_B2) bj += bias2[col];
#pragma unroll
  for (int i = 0; i < 4; ++i)
#pragma unroll
    for (int r = 0; r < 4; ++r) {
      int row = bm + i * 16 + quad * 4 + r;
      float v = acc[i][r] + bj;
      if (RELU) v = fmaxf(v, 0.f);
      if (OUT_SPLIT) {
        unsigned short hb = f2bf(v);
        Ch[(size_t)row * N + col] = hb;
        Cl[(size_t)row * N + col] = f2bf(v - bf2f(hb));
      } else {
        Cf[(size_t)row * N + col] = v;
      }
    }
}

// ---------------------------------------------------------------------------
// Pack W_hh [1024,256] fp32 -> bf16 B-fragment layout:
//   frag(nt,kt): lane holds B[n = nt*16 + (lane&15)][kt*32 + (lane>>4)*8 + j]
// ---------------------------------------------------------------------------
__global__ __launch_bounds__(256) void pack_whh(const float* __restrict__ W,
                                                unsigned short* __restrict__ o) {
  int idx = blockIdx.x * 256 + threadIdx.x;  // (nt*8+kt)*64 + lane
  int lane = idx & 63;
  int kt = (idx >> 6) & 7;
  int nt = idx >> 9;
  int n = nt * 16 + (lane & 15);
  int k0 = kt * 32 + (lane >> 4) * 8;
  const float* src = W + (size_t)n * 256 + k0;
  unsigned short* dst = o + (size_t)idx * 8;
#pragma unroll
  for (int j = 0; j < 8; ++j) dst[j] = f2bf(src[j]);
}

// ---------------------------------------------------------------------------
// Persistent LSTM: 128 blocks x 512 threads (8 waves, 2/SIMD). Block owns 32
// batch rows for all 50 steps. Wave w: u-tiles {2w,2w+1} x 4 gates x 2 m-tiles.
// B-fragments streamed from L2 with 1-kt register prefetch; raw lgkm-only
// barrier so B-loads and h-stores pipeline across steps.
// ---------------------------------------------------------------------------
__global__ __launch_bounds__(512, 2) void lstm_kernel(
    const float* __restrict__ xp,            // [4096,1024] fp32, gates i|f|g|o
    const unsigned short* __restrict__ whhf, // packed bf16 fragments
    float* __restrict__ out) {               // [4096,50,256] fp32
  __shared__ unsigned short h_frag[2][2][8][64][8];  // [buf][mt][kt][lane][j]

  const int tid = threadIdx.x;
  const int wave = tid >> 6;
  const int lane = tid & 63;
  const int quad = lane >> 4;
  const int l16 = lane & 15;
  const int block_m = blockIdx.x * 32;
  const int ut0 = wave * 2;

  for (int i = tid; i < 2 * 2 * 8 * 64 * 8; i += 512)
    ((unsigned short*)h_frag)[i] = 0;

  // x_part in registers, C-fragment layout; i = g*2 + utl
  floatx4 xpreg[2][8];
#pragma unroll
  for (int mt = 0; mt < 2; ++mt)
#pragma unroll
    for (int i = 0; i < 8; ++i) {
      int g = i >> 1, utl = i & 1;
      int col = g * 256 + (ut0 + utl) * 16 + l16;
      floatx4 v;
#pragma unroll
      for (int r = 0; r < 4; ++r)
        v[r] = xp[(size_t)(block_m + mt * 16 + quad * 4 + r) * 1024 + col];
      xpreg[mt][i] = v;
    }

  float c[2][2][4] = {};
  __syncthreads();

  const size_t orow = (size_t)TSTEPS * HID;
  int cur = 0;

#pragma unroll 1
  for (int t = 0; t < TSTEPS; ++t) {
    // launder: keep B loads inside the loop (no LICM -> no 256-reg hoist)
    const unsigned short* wb = whhf;
    asm volatile("" : "+s"(wb));

    floatx4 acc[2][8];
#pragma unroll
    for (int mt = 0; mt < 2; ++mt)
#pragma unroll
      for (int i = 0; i < 8; ++i) acc[mt][i] = xpreg[mt][i];

    // kt-pipelined B-fragment stream (double-buffered in registers)
    short8 bbuf[2][8];
#pragma unroll
    for (int i = 0; i < 8; ++i) {
      int nt = (i >> 1) * 16 + ut0 + (i & 1);
      bbuf[0][i] = *(const short8*)(wb + ((size_t)(nt * 8 + 0) * 64 + lane) * 8);
    }
#pragma unroll
    for (int kt = 0; kt < 8; ++kt) {
      if (kt < 7) {
#pragma unroll
        for (int i = 0; i < 8; ++i) {
          int nt = (i >> 1) * 16 + ut0 + (i & 1);
          bbuf[(kt + 1) & 1][i] =
              *(const short8*)(wb + ((size_t)(nt * 8 + kt + 1) * 64 + lane) * 8);
        }
      }
      short8 a0 = *(const short8*)&h_frag[cur][0][kt][lane][0];
      short8 a1 = *(const short8*)&h_frag[cur][1][kt][lane][0];
#pragma unroll
      for (int i = 0; i < 8; ++i) {
        acc[0][i] = __builtin_amdgcn_mfma_f32_16x16x32_bf16(a0, bbuf[kt & 1][i],
                                                            acc[0][i], 0, 0, 0);
        acc[1][i] = __builtin_amdgcn_mfma_f32_16x16x32_bf16(a1, bbuf[kt & 1][i],
                                                            acc[1][i], 0, 0, 0);
      }
    }

    const int nxt = cur ^ 1;
#pragma unroll
    for (int mt = 0; mt < 2; ++mt)
#pragma unroll
      for (int utl = 0; utl < 2; ++utl) {
        floatx4 gi = acc[mt][0 + utl];
        floatx4 gf = acc[mt][2 + utl];
        floatx4 gg = acc[mt][4 + utl];
        floatx4 go = acc[mt][6 + utl];
        const int u = (ut0 + utl) * 16 + l16;
        const int kt2 = u >> 5;
        const int lhi = ((u >> 3) & 3) << 4;
        const int j2 = u & 7;
#pragma unroll
        for (int r = 0; r < 4; ++r) {
          float iv = sigmf(gi[r]);
          float fv = sigmf(gf[r]);
          float gv = tanhf_(gg[r]);
          float ov = sigmf(go[r]);
          float cv = fmaf(fv, c[mt][utl][r], iv * gv);
          c[mt][utl][r] = cv;
          float hv = ov * tanhf_(cv);
          int mloc = mt * 16 + quad * 4 + r;
          __builtin_nontemporal_store(
              hv, out + (size_t)(block_m + mloc) * orow + (size_t)t * HID + u);
          h_frag[nxt][mt][kt2][(mloc & 15) | lhi][j2] = f2bf(hv);
        }
      }
    cur = nxt;
    // lgkm-only barrier: LDS h_frag visibility without draining vmcnt, so
    // B-load stream and h-stores pipeline across timesteps.
    __asm__ volatile("s_waitcnt lgkmcnt(0)\n\ts_barrier" ::: "memory");
  }
}

// ---------------------------------------------------------------------------
extern "C" void kernel_launch(void* const* d_in, const int* in_sizes, int n_in,
                              void* d_out, int out_size, void* d_ws, size_t ws_size,
                              hipStream_t stream) {
  const float* zs  = (const float*)d_in[0];
  const float* W1  = (const float*)d_in[1];
  const float* b1  = (const float*)d_in[2];
  const float* W2  = (const float*)d_in[3];
  const float* b2  = (const float*)d_in[4];
  const float* W3  = (const float*)d_in[5];
  const float* b3  = (const float*)d_in[6];
  const float* Wih = (const float*)d_in[7];
  const float* Whh = (const float*)d_in[8];
  const float* bih = (const float*)d_in[9];
  const float* bhh = (const float*)d_in[10];
  float* out = (float*)d_out;

  char* ws = (char*)d_ws;
  const size_t MB = 1024 * 1024;
  unsigned short* zs_h = (unsigned short*)(ws + 0 * MB);       // 2 MB
  unsigned short* zs_l = (unsigned short*)(ws + 2 * MB);       // 2 MB
  unsigned short* h1_h = (unsigned short*)(ws + 4 * MB);       // 4 MB
  unsigned short* h1_l = (unsigned short*)(ws + 8 * MB);       // 4 MB
  unsigned short* h2_h = (unsigned short*)(ws + 0 * MB);       // reuse zs (2 MB)
  unsigned short* h2_l = (unsigned short*)(ws + 2 * MB);       // reuse zs (2 MB)
  unsigned short* zb_h = (unsigned short*)(ws + 12 * MB);      // 1 MB
  unsigned short* zb_l = (unsigned short*)(ws + 13 * MB);      // 1 MB
  unsigned short* w1_h = (unsigned short*)(ws + 14 * MB);                 // 256 KB
  unsigned short* w1_l = (unsigned short*)(ws + 14 * MB + 256 * 1024);
  unsigned short* w2_h = (unsigned short*)(ws + 14 * MB + 512 * 1024);
  unsigned short* w2_l = (unsigned short*)(ws + 14 * MB + 768 * 1024);
  unsigned short* w3_h = (unsigned short*)(ws + 15 * MB);                 // 64 KB
  unsigned short* w3_l = (unsigned short*)(ws + 15 * MB + 64 * 1024);
  unsigned short* wi_h = (unsigned short*)(ws + 15 * MB + 128 * 1024);    // 256 KB
  unsigned short* wi_l = (unsigned short*)(ws + 15 * MB + 384 * 1024);
  float* xp            = (float*)(ws + 16 * MB);               // 16 MB
  unsigned short* whhf = (unsigned short*)(ws + 32 * MB);      // 512 KB

  // fp32 -> hi/lo bf16 splits
  split_bf<<<(1048576 / 4 + 255) / 256, 256, 0, stream>>>(zs, zs_h, zs_l, 1048576 / 4);
  split_bf<<<(131072 / 4 + 255) / 256, 256, 0, stream>>>(W1, w1_h, w1_l, 131072 / 4);
  split_bf<<<(131072 / 4 + 255) / 256, 256, 0, stream>>>(W2, w2_h, w2_l, 131072 / 4);
  split_bf<<<(32768 / 4 + 255) / 256, 256, 0, stream>>>(W3, w3_h, w3_l, 32768 / 4);
  split_bf<<<(131072 / 4 + 255) / 256, 256, 0, stream>>>(Wih, wi_h, wi_l, 131072 / 4);

  // MLP: h1 = relu(zs@W1^T+b1); h2 = relu(h1@W2^T+b2); zb = h2@W3^T+b3
  gemm_df<1, 1, 0><<<dim3(512 / 64, BATCH / 64), 256, 0, stream>>>(
      zs_h, zs_l, w1_h, w1_l, b1, nullptr, nullptr, h1_h, h1_l, BATCH, 512, 256);
  gemm_df<1, 1, 0><<<dim3(256 / 64, BATCH / 64), 256, 0, stream>>>(
      h1_h, h1_l, w2_h, w2_l, b2, nullptr, nullptr, h2_h, h2_l, BATCH, 256, 512);
  gemm_df<0, 1, 0><<<dim3(128 / 64, BATCH / 64), 256, 0, stream>>>(
      h2_h, h2_l, w3_h, w3_l, b3, nullptr, nullptr, zb_h, zb_l, BATCH, 128, 256);
  // xp = zb@Wih^T + b_ih + b_hh  (fp32 out)
  gemm_df<0, 0, 1><<<dim3(1024 / 64, BATCH / 64), 256, 0, stream>>>(
      zb_h, zb_l, wi_h, wi_l, bih, bhh, xp, nullptr, nullptr, BATCH, 1024, 128);

  pack_whh<<<128, 256, 0, stream>>>(Whh, whhf);

  lstm_kernel<<<BATCH / 32, 512, 0, stream>>>(xp, whhf, out);
}

// Round 3
// 673.254 us; speedup vs baseline: 1.3392x; 1.2642x over previous
//
#include <hip/hip_runtime.h>
#include <stdint.h>

// ---------------------------------------------------------------------------
// Predictor: MLP (256->512->256->128) -> LSTM(128 in, 256 hidden, T=50)
//   - MLP via split-bf16 (hi+lo) MFMA gemms, lgkm-only barriers + tile
//     prefetch so global latency overlaps MFMA.
//   - LSTM: 128 blocks x 512 thr, M=32 rows/block, 50 steps in-kernel.
//     W_hh bf16 fragments streamed from L2 with a PERSISTENT rolling
//     register prefetch (next step's kt=0 issues before this step's output
//     stores -> no vmcnt(0) store-drain on the critical path). Plain (L2)
//     output stores. lgkm-only step barrier. c-state in VGPRs; h
//     double-buffered in LDS in A-fragment layout.
// ---------------------------------------------------------------------------

typedef short short8 __attribute__((ext_vector_type(8)));
typedef float floatx4 __attribute__((ext_vector_type(4)));
typedef unsigned short ushort4v __attribute__((ext_vector_type(4)));

#define BATCH 4096
#define HID 256
#define TSTEPS 50

static __device__ __forceinline__ unsigned short f2bf(float x) {
  union { float f; unsigned int u; } v; v.f = x;
  unsigned int r = (v.u + 0x7fffu + ((v.u >> 16) & 1u)) >> 16;  // RNE
  return (unsigned short)r;
}
static __device__ __forceinline__ float bf2f(unsigned short h) {
  union { unsigned int u; float f; } v; v.u = ((unsigned int)h) << 16;
  return v.f;
}
static __device__ __forceinline__ float sigmf(float x) {
  return __builtin_amdgcn_rcpf(1.0f + __expf(-x));
}
static __device__ __forceinline__ float tanhf_(float x) {
  return 1.0f - 2.0f * __builtin_amdgcn_rcpf(__expf(2.0f * x) + 1.0f);
}

// lgkm-only barrier: LDS visibility without draining the vmcnt queue.
static __device__ __forceinline__ void lds_barrier() {
  __asm__ volatile("s_waitcnt lgkmcnt(0)\n\ts_barrier" ::: "memory");
}

// ---------------------------------------------------------------------------
// Fused fp32 -> (hi,lo) bf16 split for all 5 arrays in one launch.
// Work item = one float4. Segment boundaries (in float4 units) hard-coded.
// ---------------------------------------------------------------------------
__global__ __launch_bounds__(256) void split_all(
    const float* __restrict__ s0, unsigned short* __restrict__ h0, unsigned short* __restrict__ l0,
    const float* __restrict__ s1, unsigned short* __restrict__ h1, unsigned short* __restrict__ l1,
    const float* __restrict__ s2, unsigned short* __restrict__ h2, unsigned short* __restrict__ l2,
    const float* __restrict__ s3, unsigned short* __restrict__ h3, unsigned short* __restrict__ l3,
    const float* __restrict__ s4, unsigned short* __restrict__ h4, unsigned short* __restrict__ l4) {
  int i = blockIdx.x * 256 + threadIdx.x;
  const float* src; unsigned short *dh, *dl; int off;
  if (i < 262144)      { src = s0; dh = h0; dl = l0; off = i; }
  else if (i < 294912) { src = s1; dh = h1; dl = l1; off = i - 262144; }
  else if (i < 327680) { src = s2; dh = h2; dl = l2; off = i - 294912; }
  else if (i < 335872) { src = s3; dh = h3; dl = l3; off = i - 327680; }
  else if (i < 368640) { src = s4; dh = h4; dl = l4; off = i - 335872; }
  else return;
  float4 v = ((const float4*)src)[off];
  float cc[4] = {v.x, v.y, v.z, v.w};
  ushort4v h, l;
#pragma unroll
  for (int j = 0; j < 4; ++j) {
    unsigned short hb = f2bf(cc[j]);
    h[j] = hb;
    l[j] = f2bf(cc[j] - bf2f(hb));
  }
  ((ushort4v*)dh)[off] = h;
  ((ushort4v*)dl)[off] = l;
}

// ---------------------------------------------------------------------------
// Split-bf16 MFMA GEMM: C = act(A @ B^T + bias (+bias2)), A:[M,K], B:[N,K]
// hi/lo bf16 pairs, row-major. 64x64 tile, 256 thr, BK=32, XOR-swizzled LDS.
// Pipelined: next k-tile's global loads issue before this tile's MFMAs;
// lgkm-only barriers keep the vmcnt queue flowing.
// ---------------------------------------------------------------------------
template <int RELU, int OUT_SPLIT, int HAS_B2>
__global__ __launch_bounds__(256) void gemm_df(
    const unsigned short* __restrict__ Ah, const unsigned short* __restrict__ Al,
    const unsigned short* __restrict__ Bh, const unsigned short* __restrict__ Bl,
    const float* __restrict__ bias, const float* __restrict__ bias2,
    float* __restrict__ Cf, unsigned short* __restrict__ Ch,
    unsigned short* __restrict__ Cl, int M, int N, int K) {
  __shared__ unsigned short Ash[64 * 32], Asl[64 * 32];
  __shared__ unsigned short Bsh[64 * 32], Bsl[64 * 32];
  const int tid = threadIdx.x;
  const int wave = tid >> 6, lane = tid & 63;
  const int quad = lane >> 4, l16 = lane & 15;
  const int bm = blockIdx.y * 64, bn = blockIdx.x * 64;
  const int lr = tid >> 2, lc = tid & 3;
  const int wofs = lr * 32 + ((lc ^ (lr & 3)) * 8);  // swizzled 16B chunk

  floatx4 acc[4] = {};
  // preload k-tile 0
  short8 avh = *(const short8*)(Ah + (size_t)(bm + lr) * K + lc * 8);
  short8 avl = *(const short8*)(Al + (size_t)(bm + lr) * K + lc * 8);
  short8 bvh = *(const short8*)(Bh + (size_t)(bn + lr) * K + lc * 8);
  short8 bvl = *(const short8*)(Bl + (size_t)(bn + lr) * K + lc * 8);

  for (int k0 = 0; k0 < K; k0 += 32) {
    lds_barrier();  // prior tile's LDS reads complete
    *(short8*)&Ash[wofs] = avh;
    *(short8*)&Asl[wofs] = avl;
    *(short8*)&Bsh[wofs] = bvh;
    *(short8*)&Bsl[wofs] = bvl;
    lds_barrier();
    if (k0 + 32 < K) {  // issue next tile's loads; MFMAs below hide latency
      avh = *(const short8*)(Ah + (size_t)(bm + lr) * K + k0 + 32 + lc * 8);
      avl = *(const short8*)(Al + (size_t)(bm + lr) * K + k0 + 32 + lc * 8);
      bvh = *(const short8*)(Bh + (size_t)(bn + lr) * K + k0 + 32 + lc * 8);
      bvl = *(const short8*)(Bl + (size_t)(bn + lr) * K + k0 + 32 + lc * 8);
    }
    const int bro = (wave * 16 + l16) * 32 + ((quad ^ (l16 & 3)) * 8);
    short8 bh = *(const short8*)&Bsh[bro];
    short8 bl = *(const short8*)&Bsl[bro];
#pragma unroll
    for (int i = 0; i < 4; ++i) {
      const int aro = (i * 16 + l16) * 32 + ((quad ^ (l16 & 3)) * 8);
      short8 ah = *(const short8*)&Ash[aro];
      short8 al = *(const short8*)&Asl[aro];
      acc[i] = __builtin_amdgcn_mfma_f32_16x16x32_bf16(al, bh, acc[i], 0, 0, 0);
      acc[i] = __builtin_amdgcn_mfma_f32_16x16x32_bf16(ah, bl, acc[i], 0, 0, 0);
      acc[i] = __builtin_amdgcn_mfma_f32_16x16x32_bf16(ah, bh, acc[i], 0, 0, 0);
    }
  }
  const int col = bn + wave * 16 + l16;
  float bj = bias[col];
  if (HAS_B2) bj += bias2[col];
#pragma unroll
  for (int i = 0; i < 4; ++i)
#pragma unroll
    for (int r = 0; r < 4; ++r) {
      int row = bm + i * 16 + quad * 4 + r;
      float v = acc[i][r] + bj;
      if (RELU) v = fmaxf(v, 0.f);
      if (OUT_SPLIT) {
        unsigned short hb = f2bf(v);
        Ch[(size_t)row * N + col] = hb;
        Cl[(size_t)row * N + col] = f2bf(v - bf2f(hb));
      } else {
        Cf[(size_t)row * N + col] = v;
      }
    }
}

// ---------------------------------------------------------------------------
// Pack W_hh [1024,256] fp32 -> bf16 B-fragment layout:
//   frag(nt,kt): lane holds B[n = nt*16 + (lane&15)][kt*32 + (lane>>4)*8 + j]
// ---------------------------------------------------------------------------
__global__ __launch_bounds__(256) void pack_whh(const float* __restrict__ W,
                                                unsigned short* __restrict__ o) {
  int idx = blockIdx.x * 256 + threadIdx.x;  // (nt*8+kt)*64 + lane
  int lane = idx & 63;
  int kt = (idx >> 6) & 7;
  int nt = idx >> 9;
  int n = nt * 16 + (lane & 15);
  int k0 = kt * 32 + (lane >> 4) * 8;
  const float* src = W + (size_t)n * 256 + k0;
  unsigned short* dst = o + (size_t)idx * 8;
#pragma unroll
  for (int j = 0; j < 8; ++j) dst[j] = f2bf(src[j]);
}

// ---------------------------------------------------------------------------
// Persistent LSTM: 128 blocks x 512 threads (8 waves, 2/SIMD). Block owns 32
// batch rows for all 50 steps. Wave w: u-tiles {2w,2w+1} x 4 gates x 2 m-tiles.
// Rolling B prefetch persists ACROSS steps (kt=0 of step t+1 issues during
// kt=7 of step t, ahead of the output stores in the vmcnt FIFO).
// ---------------------------------------------------------------------------
__global__ __launch_bounds__(512, 2) void lstm_kernel(
    const float* __restrict__ xp,            // [4096,1024] fp32, gates i|f|g|o
    const unsigned short* __restrict__ whhf, // packed bf16 fragments
    float* __restrict__ out) {               // [4096,50,256] fp32
  __shared__ unsigned short h_frag[2][2][8][64][8];  // [buf][mt][kt][lane][j]

  const int tid = threadIdx.x;
  const int wave = tid >> 6;
  const int lane = tid & 63;
  const int quad = lane >> 4;
  const int l16 = lane & 15;
  const int block_m = blockIdx.x * 32;
  const int ut0 = wave * 2;

  for (int i = tid; i < 2 * 2 * 8 * 64 * 8; i += 512)
    ((unsigned short*)h_frag)[i] = 0;

  // x_part in registers, C-fragment layout; i = g*2 + utl
  floatx4 xpreg[2][8];
#pragma unroll
  for (int mt = 0; mt < 2; ++mt)
#pragma unroll
    for (int i = 0; i < 8; ++i) {
      int g = i >> 1, utl = i & 1;
      int col = g * 256 + (ut0 + utl) * 16 + l16;
      floatx4 v;
#pragma unroll
      for (int r = 0; r < 4; ++r)
        v[r] = xp[(size_t)(block_m + mt * 16 + quad * 4 + r) * 1024 + col];
      xpreg[mt][i] = v;
    }

  float c[2][2][4] = {};

  // Persistent rolling B-fragment pipeline (lives across timesteps).
  short8 bbuf[2][8];
#pragma unroll
  for (int i = 0; i < 8; ++i) {
    int nt = (i >> 1) * 16 + ut0 + (i & 1);
    bbuf[0][i] = *(const short8*)(whhf + ((size_t)(nt * 8 + 0) * 64 + lane) * 8);
  }

  __syncthreads();

  const size_t orow = (size_t)TSTEPS * HID;
  int cur = 0;

#pragma unroll 1
  for (int t = 0; t < TSTEPS; ++t) {
    // launder: keep B loads inside the loop (no LICM -> no 256-reg hoist)
    const unsigned short* wb = whhf;
    asm volatile("" : "+s"(wb));

    floatx4 acc[2][8];
#pragma unroll
    for (int mt = 0; mt < 2; ++mt)
#pragma unroll
      for (int i = 0; i < 8; ++i) acc[mt][i] = xpreg[mt][i];

#pragma unroll
    for (int kt = 0; kt < 8; ++kt) {
      // Unconditional rolling prefetch: kt==7 fetches next step's kt=0
      // (same t-invariant address), issued BEFORE this step's stores.
      const int ktn = (kt + 1) & 7;
#pragma unroll
      for (int i = 0; i < 8; ++i) {
        int nt = (i >> 1) * 16 + ut0 + (i & 1);
        bbuf[ktn & 1][i] =
            *(const short8*)(wb + ((size_t)(nt * 8 + ktn) * 64 + lane) * 8);
      }
      short8 a0 = *(const short8*)&h_frag[cur][0][kt][lane][0];
      short8 a1 = *(const short8*)&h_frag[cur][1][kt][lane][0];
#pragma unroll
      for (int i = 0; i < 8; ++i) {
        acc[0][i] = __builtin_amdgcn_mfma_f32_16x16x32_bf16(a0, bbuf[kt & 1][i],
                                                            acc[0][i], 0, 0, 0);
        acc[1][i] = __builtin_amdgcn_mfma_f32_16x16x32_bf16(a1, bbuf[kt & 1][i],
                                                            acc[1][i], 0, 0, 0);
      }
    }

    const int nxt = cur ^ 1;
#pragma unroll
    for (int mt = 0; mt < 2; ++mt)
#pragma unroll
      for (int utl = 0; utl < 2; ++utl) {
        floatx4 gi = acc[mt][0 + utl];
        floatx4 gf = acc[mt][2 + utl];
        floatx4 gg = acc[mt][4 + utl];
        floatx4 go = acc[mt][6 + utl];
        const int u = (ut0 + utl) * 16 + l16;
        const int kt2 = u >> 5;
        const int lhi = ((u >> 3) & 3) << 4;
        const int j2 = u & 7;
#pragma unroll
        for (int r = 0; r < 4; ++r) {
          float iv = sigmf(gi[r]);
          float fv = sigmf(gf[r]);
          float gv = tanhf_(gg[r]);
          float ov = sigmf(go[r]);
          float cv = fmaf(fv, c[mt][utl][r], iv * gv);
          c[mt][utl][r] = cv;
          float hv = ov * tanhf_(cv);
          int mloc = mt * 16 + quad * 4 + r;
          // plain store: retires at L2 ack, not HBM
          out[(size_t)(block_m + mloc) * orow + (size_t)t * HID + u] = hv;
          h_frag[nxt][mt][kt2][(mloc & 15) | lhi][j2] = f2bf(hv);
        }
      }
    cur = nxt;
    lds_barrier();  // h_frag visibility only; vmcnt queue keeps flowing
  }
}

// ---------------------------------------------------------------------------
extern "C" void kernel_launch(void* const* d_in, const int* in_sizes, int n_in,
                              void* d_out, int out_size, void* d_ws, size_t ws_size,
                              hipStream_t stream) {
  const float* zs  = (const float*)d_in[0];
  const float* W1  = (const float*)d_in[1];
  const float* b1  = (const float*)d_in[2];
  const float* W2  = (const float*)d_in[3];
  const float* b2  = (const float*)d_in[4];
  const float* W3  = (const float*)d_in[5];
  const float* b3  = (const float*)d_in[6];
  const float* Wih = (const float*)d_in[7];
  const float* Whh = (const float*)d_in[8];
  const float* bih = (const float*)d_in[9];
  const float* bhh = (const float*)d_in[10];
  float* out = (float*)d_out;

  char* ws = (char*)d_ws;
  const size_t MB = 1024 * 1024;
  unsigned short* zs_h = (unsigned short*)(ws + 0 * MB);       // 2 MB
  unsigned short* zs_l = (unsigned short*)(ws + 2 * MB);       // 2 MB
  unsigned short* h1_h = (unsigned short*)(ws + 4 * MB);       // 4 MB
  unsigned short* h1_l = (unsigned short*)(ws + 8 * MB);       // 4 MB
  unsigned short* h2_h = (unsigned short*)(ws + 0 * MB);       // reuse zs (2 MB)
  unsigned short* h2_l = (unsigned short*)(ws + 2 * MB);       // reuse zs (2 MB)
  unsigned short* zb_h = (unsigned short*)(ws + 12 * MB);      // 1 MB
  unsigned short* zb_l = (unsigned short*)(ws + 13 * MB);      // 1 MB
  unsigned short* w1_h = (unsigned short*)(ws + 14 * MB);                 // 256 KB
  unsigned short* w1_l = (unsigned short*)(ws + 14 * MB + 256 * 1024);
  unsigned short* w2_h = (unsigned short*)(ws + 14 * MB + 512 * 1024);
  unsigned short* w2_l = (unsigned short*)(ws + 14 * MB + 768 * 1024);
  unsigned short* w3_h = (unsigned short*)(ws + 15 * MB);                 // 64 KB
  unsigned short* w3_l = (unsigned short*)(ws + 15 * MB + 64 * 1024);
  unsigned short* wi_h = (unsigned short*)(ws + 15 * MB + 128 * 1024);    // 256 KB
  unsigned short* wi_l = (unsigned short*)(ws + 15 * MB + 384 * 1024);
  float* xp            = (float*)(ws + 16 * MB);               // 16 MB
  unsigned short* whhf = (unsigned short*)(ws + 32 * MB);      // 512 KB

  // fp32 -> hi/lo bf16 splits, one fused launch (zs, W1, W2, W3, Wih)
  split_all<<<1440, 256, 0, stream>>>(zs, zs_h, zs_l, W1, w1_h, w1_l,
                                      W2, w2_h, w2_l, W3, w3_h, w3_l,
                                      Wih, wi_h, wi_l);

  // MLP: h1 = relu(zs@W1^T+b1); h2 = relu(h1@W2^T+b2); zb = h2@W3^T+b3
  gemm_df<1, 1, 0><<<dim3(512 / 64, BATCH / 64), 256, 0, stream>>>(
      zs_h, zs_l, w1_h, w1_l, b1, nullptr, nullptr, h1_h, h1_l, BATCH, 512, 256);
  gemm_df<1, 1, 0><<<dim3(256 / 64, BATCH / 64), 256, 0, stream>>>(
      h1_h, h1_l, w2_h, w2_l, b2, nullptr, nullptr, h2_h, h2_l, BATCH, 256, 512);
  gemm_df<0, 1, 0><<<dim3(128 / 64, BATCH / 64), 256, 0, stream>>>(
      h2_h, h2_l, w3_h, w3_l, b3, nullptr, nullptr, zb_h, zb_l, BATCH, 128, 256);
  // xp = zb@Wih^T + b_ih + b_hh  (fp32 out)
  gemm_df<0, 0, 1><<<dim3(1024 / 64, BATCH / 64), 256, 0, stream>>>(
      zb_h, zb_l, wi_h, wi_l, bih, bhh, xp, nullptr, nullptr, BATCH, 1024, 128);

  pack_whh<<<128, 256, 0, stream>>>(Whh, whhf);

  lstm_kernel<<<BATCH / 32, 512, 0, stream>>>(xp, whhf, out);
}